// Round 2
// baseline (447.040 us; speedup 1.0000x reference)
//
#include <hip/hip_runtime.h>
#include <stdint.h>

#define B_ 8
#define S_ 1024
#define D_ 1024
#define H_ 2048
#define E_ 8
#define DN_ 256

typedef unsigned char u8;
typedef float f32x4 __attribute__((ext_vector_type(4)));
typedef long long ll;

// fp8 e4m3 (OCP on gfx950) converts
__device__ __forceinline__ u8 f2f8(float f) {
  return (u8)(__builtin_amdgcn_cvt_pk_fp8_f32(f, f, 0, false) & 0xff);
}
__device__ __forceinline__ unsigned int pk4f8(float a, float b, float c, float d) {
  int w = __builtin_amdgcn_cvt_pk_fp8_f32(a, b, 0, false);
  w = __builtin_amdgcn_cvt_pk_fp8_f32(c, d, w, true);
  return (unsigned int)w;
}

// async global->LDS, 16B per lane. LDS dest is wave-uniform base; HW adds lane*16.
__device__ __forceinline__ void gll16(const void* g, void* l) {
  __builtin_amdgcn_global_load_lds(
      (__attribute__((address_space(1))) void*)g,
      (__attribute__((address_space(3))) void*)l, 16, 0, 0);
}

// swizzle value for tile row r (16B-pair XOR): 2-way-max bank conflicts on b64 frag reads
__device__ __forceinline__ int swz(int r) { return (r & 3) ^ ((r >> 2) & 1); }

// ---------------- merged prep: router + cast x + transpose/cast weights ----------------
template <int R, int C>
__device__ __forceinline__ void transpose_body(const float* __restrict__ ip,
                                               u8* __restrict__ op,
                                               int bx, int by, int t,
                                               u8 (&tile)[64][72]) {
  const int r0 = by * 64, c0 = bx * 64;
  const int rr = t >> 4;        // 0..15
  const int c4 = t & 15;        // 0..15 (group of 4 cols)
#pragma unroll
  for (int i = 0; i < 4; ++i) {
    const int r = rr + i * 16;
    float4 v = *(const float4*)(ip + (size_t)(r0 + r) * C + c0 + c4 * 4);
    tile[c4 * 4 + 0][r] = f2f8(v.x);
    tile[c4 * 4 + 1][r] = f2f8(v.y);
    tile[c4 * 4 + 2][r] = f2f8(v.z);
    tile[c4 * 4 + 3][r] = f2f8(v.w);
  }
  __syncthreads();
#pragma unroll
  for (int i = 0; i < 4; ++i) {
    const int c = rr + i * 16;
    unsigned int w = *(const unsigned int*)&tile[c][c4 * 4];
    *(unsigned int*)(op + (size_t)(c0 + c) * R + r0 + c4 * 4) = w;
  }
}

#define NCAST (B_ * S_ * D_ / 1024)            // 8192 blocks (256 thr x float4)
#define NT1 ((2 * H_ / 64) * (D_ / 64) * E_)   // 8192 blocks
#define NT2 ((D_ / 64) * (H_ / 64) * E_)       // 4096 blocks

__global__ void __launch_bounds__(256) prep_kernel(
    const float* __restrict__ x, const float* __restrict__ noise,
    const float* __restrict__ rw, const float* __restrict__ fiw,
    const float* __restrict__ fow,
    float* __restrict__ out_logits, float* __restrict__ out_probs,
    float* __restrict__ out_idx, float* __restrict__ out_w,
    int* __restrict__ ws_idx, float* __restrict__ ws_w,
    unsigned int* __restrict__ xq, u8* __restrict__ wtin,
    u8* __restrict__ wtout) {
  __shared__ __align__(16) u8 tile[64][72];
  const int t = threadIdx.x;
  int bid = blockIdx.x;

  if (bid == 0) {  // -------- router (hidden under the memory-bound blocks) ------
    float* sl = (float*)&tile[0][0];
    float* sp = sl + 64;
    {
      const int pair = t >> 2, sub = t & 3;      // 64 (b,e) pairs x 4 threads
      const int b = pair >> 3, e = pair & 7;
      float acc = 0.f;
      const int d0 = sub * 64;
      for (int d = d0; d < d0 + 64; ++d)
        acc += noise[b * DN_ + d] * rw[d * E_ + e];
      acc += __shfl_xor(acc, 1);
      acc += __shfl_xor(acc, 2);
      if (sub == 0) sl[pair] = acc;
    }
    __syncthreads();
    if (t < 64) {
      const int b = t >> 3;
      float L = sl[t];
      out_logits[t] = L;
      float m = -1e30f;
      for (int j = 0; j < 8; ++j) m = fmaxf(m, sl[b * 8 + j]);
      float s = 0.f;
      for (int j = 0; j < 8; ++j) s += __expf(sl[b * 8 + j] - m);
      float p = __expf(L - m) / s;
      out_probs[t] = p;
      sp[t] = p;
    }
    __syncthreads();
    if (t < 64 && (t & 7) == 0) {
      const int b = t >> 3;
      int a1 = 0; float v1 = sp[b * 8];
      for (int j = 1; j < 8; ++j) { float v = sp[b * 8 + j]; if (v > v1) { v1 = v; a1 = j; } }
      int a2 = -1; float v2 = -1e30f;
      for (int j = 0; j < 8; ++j) {
        if (j == a1) continue;
        float v = sp[b * 8 + j]; if (v > v2) { v2 = v; a2 = j; }
      }
      float sum = fmaxf(v1 + v2, 1e-8f);
      float w1 = v1 / sum, w2 = v2 / sum;
      out_idx[b * 2] = (float)a1; out_idx[b * 2 + 1] = (float)a2;
      out_w[b * 2] = w1; out_w[b * 2 + 1] = w2;
      ws_idx[b * 2] = a1; ws_idx[b * 2 + 1] = a2;
      ws_w[b * 2] = w1; ws_w[b * 2 + 1] = w2;
    }
    return;
  }
  bid -= 1;
  if (bid < NCAST) {  // -------- cast x -> fp8 --------
    const size_t i = (size_t)bid * 256 + t;
    float4 v = *((const float4*)x + i);
    xq[i] = pk4f8(v.x, v.y, v.z, v.w);
    return;
  }
  bid -= NCAST;
  if (bid < NT1) {  // -------- fc_in_w [E][D][2H] f32 -> [E][2H][D] fp8 --------
    const int bx = bid & 63, by = (bid >> 6) & 15, e = bid >> 10;
    transpose_body<D_, 2 * H_>(fiw + (size_t)e * D_ * 2 * H_,
                               wtin + (size_t)e * D_ * 2 * H_, bx, by, t, tile);
    return;
  }
  bid -= NT1;
  {  // -------- fc_out_w [E][H][D] f32 -> [E][D][H] fp8 --------
    const int bx = bid & 15, by = (bid >> 4) & 31, e = bid >> 9;
    transpose_body<H_, D_>(fow + (size_t)e * H_ * D_,
                           wtout + (size_t)e * H_ * D_, bx, by, t, tile);
  }
}

// ---------------- GEMM1: hidden = silu-gated(x @ W_in + b_in) * coeff  (fp8, BK=64) ----
// Block tile: 128 s-rows x 64 hid-cols (value + gate share one B-tile).
// 2-phase pipeline: double-buffered LDS, stage(k+1) issued BEFORE compute(k),
// single __syncthreads per K-step (vmcnt(0) drain lands after MFMA cluster).
__global__ void __launch_bounds__(256, 4) gemm1_kernel(
    const u8* __restrict__ xq,      // [B][S][D] fp8
    const u8* __restrict__ wtin,    // [E][2H][D] fp8 (pre-transposed)
    const float* __restrict__ bin,  // [E][2H] f32
    const int* __restrict__ ws_idx, const float* __restrict__ ws_w,
    u8* __restrict__ hid)           // [B*2][S][H] fp8
{
  const int nt = blockIdx.x;   // 32 tiles of 64 hid-cols
  const int mt = blockIdx.y;   // 8 s-tiles
  const int z  = blockIdx.z;   // 16 = b*2+slot
  const int b  = z >> 1;
  const int e  = ws_idx[z] & 7;
  const float csc = ws_w[z];

  __shared__ u8 As[2][128 * 64];   // 16 KB
  __shared__ u8 Bs[2][128 * 64];   // 16 KB: rows 0-63 value cols, 64-127 gate cols

  const int t = threadIdx.x;
  const int wave = t >> 6, lane = t & 63;
  const int wm = wave >> 1, wn = wave & 1;
  const int lm = lane & 15, lq = lane >> 4;
  const int lrow4 = lane >> 2;
  const int kq = ((lane & 3) ^ swz(lrow4)) * 16;
  const int fsw = swz(lm);
  const int p0 = lq >> 1, fb = (lq & 1) * 8;

  const u8* Ab  = xq + (size_t)b * (S_ * D_) + (size_t)mt * 128 * D_;
  const u8* Bvb = wtin + (size_t)e * (2 * H_ * D_) + (size_t)nt * 64 * D_;
  const u8* Bgb = Bvb + (size_t)H_ * D_;

  auto stage = [&](int bf, int kt) {
    const int k0 = kt * 64 + kq;
    gll16(Ab + (size_t)(wave * 16 + lrow4) * D_ + k0, (char*)As[bf] + wave * 1024);
    gll16(Ab + (size_t)((wave + 4) * 16 + lrow4) * D_ + k0, (char*)As[bf] + (wave + 4) * 1024);
    gll16(Bvb + (size_t)(wave * 16 + lrow4) * D_ + k0, (char*)Bs[bf] + wave * 1024);
    gll16(Bgb + (size_t)(wave * 16 + lrow4) * D_ + k0, (char*)Bs[bf] + 4096 + wave * 1024);
  };

  const f32x4 vz = {0.f, 0.f, 0.f, 0.f};
  f32x4 accv[4][2], accg[4][2];
#pragma unroll
  for (int i = 0; i < 4; ++i)
#pragma unroll
    for (int j = 0; j < 2; ++j) { accv[i][j] = vz; accg[i][j] = vz; }

  stage(0, 0);
  __syncthreads();
  int cur = 0;
#pragma unroll 2
  for (int kt = 0; kt < D_ / 64; ++kt) {             // 16 k-iters
    if (kt + 1 < D_ / 64) stage(cur ^ 1, kt + 1);    // prefetch next tile (async)
    const u8* Asc = As[cur];
    const u8* Bsc = Bs[cur];
    ll af[4][2], bvf[2][2], bgf[2][2];
#pragma unroll
    for (int h = 0; h < 2; ++h) {
      const int pw = ((h * 2 + p0) ^ fsw) * 16 + fb;
#pragma unroll
      for (int i = 0; i < 4; ++i)
        af[i][h] = *(const ll*)(Asc + (wm * 64 + i * 16 + lm) * 64 + pw);
#pragma unroll
      for (int j = 0; j < 2; ++j) {
        bvf[j][h] = *(const ll*)(Bsc + (wn * 32 + j * 16 + lm) * 64 + pw);
        bgf[j][h] = *(const ll*)(Bsc + (64 + wn * 32 + j * 16 + lm) * 64 + pw);
      }
    }
#pragma unroll
    for (int h = 0; h < 2; ++h)
#pragma unroll
      for (int i = 0; i < 4; ++i)
#pragma unroll
        for (int j = 0; j < 2; ++j) {
          accv[i][j] = __builtin_amdgcn_mfma_f32_16x16x32_fp8_fp8(af[i][h], bvf[j][h], accv[i][j], 0, 0, 0);
          accg[i][j] = __builtin_amdgcn_mfma_f32_16x16x32_fp8_fp8(af[i][h], bgf[j][h], accg[i][j], 0, 0, 0);
        }
    __syncthreads();   // drains vmcnt(0): prefetch had full compute phase to land
    cur ^= 1;
  }

  u8* hb = hid + (size_t)z * (S_ * H_);
  const int row0 = mt * 128 + wm * 64;
  const int col0 = nt * 64 + wn * 32;
#pragma unroll
  for (int j = 0; j < 2; ++j) {
    const int col = col0 + j * 16 + lm;
    const float bvx = bin[e * 2 * H_ + col];
    const float bgx = bin[e * 2 * H_ + H_ + col];
#pragma unroll
    for (int i = 0; i < 4; ++i) {
#pragma unroll
      for (int r = 0; r < 4; ++r) {
        const int srow = row0 + i * 16 + lq * 4 + r;
        float v = accv[i][j][r] + bvx;
        float g = accg[i][j][r] + bgx;
        float hv = v * g / (1.f + __expf(-g)) * csc;   // value * silu(gate) * coeff
        hb[(size_t)srow * H_ + col] = f2f8(hv);
      }
    }
  }
}

// ---------------- GEMM2: mixed[b] = sum_slots hidden[b,slot] @ W_out[e] + bias (fp8) ---
// 128x64 tiles, 2-phase pipeline, slot loop flattened so prefetch crosses the
// slot boundary (64 K-steps total).
__global__ void __launch_bounds__(256, 4) gemm2_kernel(
    const u8* __restrict__ hid,     // [B*2][S][H] fp8 (coeff pre-applied)
    const u8* __restrict__ wtout,   // [E][D][H] fp8 (pre-transposed)
    const float* __restrict__ bout, // [E][D] f32
    const int* __restrict__ ws_idx, const float* __restrict__ ws_w,
    float* __restrict__ out)        // [B][S][D] f32
{
  const int nt = blockIdx.x;  // 16 d-tiles of 64
  const int mt = blockIdx.y;  // 8 s-tiles of 128
  const int b  = blockIdx.z;  // 8

  __shared__ u8 As[2][128 * 64];  // 16 KB
  __shared__ u8 Bs[2][64 * 64];   // 8 KB

  const int t = threadIdx.x;
  const int wave = t >> 6, lane = t & 63;
  const int wm = wave >> 1, wn = wave & 1;
  const int lm = lane & 15, lq = lane >> 4;
  const int lrow4 = lane >> 2;
  const int kq = ((lane & 3) ^ swz(lrow4)) * 16;
  const int fsw = swz(lm);
  const int p0 = lq >> 1, fb = (lq & 1) * 8;

  const int e0 = ws_idx[b * 2] & 7, e1 = ws_idx[b * 2 + 1] & 7;
  const u8* Ab0 = hid + ((size_t)(b * 2 + 0) * S_ + mt * 128) * H_;
  const u8* Ab1 = hid + ((size_t)(b * 2 + 1) * S_ + mt * 128) * H_;
  const u8* Bb0 = wtout + ((size_t)e0 * D_ + nt * 64) * H_;
  const u8* Bb1 = wtout + ((size_t)e1 * D_ + nt * 64) * H_;

  auto stage = [&](int bf, int it) {
    const u8* Ab = (it & 32) ? Ab1 : Ab0;
    const u8* Bb = (it & 32) ? Bb1 : Bb0;
    const int k0 = (it & 31) * 64 + kq;
    gll16(Ab + (size_t)(wave * 16 + lrow4) * H_ + k0, (char*)As[bf] + wave * 1024);
    gll16(Ab + (size_t)((wave + 4) * 16 + lrow4) * H_ + k0, (char*)As[bf] + (wave + 4) * 1024);
    gll16(Bb + (size_t)(wave * 16 + lrow4) * H_ + k0, (char*)Bs[bf] + wave * 1024);
  };

  const f32x4 vz = {0.f, 0.f, 0.f, 0.f};
  f32x4 acc[4][2];
#pragma unroll
  for (int i = 0; i < 4; ++i)
#pragma unroll
    for (int j = 0; j < 2; ++j) acc[i][j] = vz;

  stage(0, 0);
  __syncthreads();
  int cur = 0;
#pragma unroll 2
  for (int it = 0; it < 64; ++it) {                  // 2 slots x 32 k-iters
    if (it + 1 < 64) stage(cur ^ 1, it + 1);         // prefetch next tile (async)
    const u8* Asc = As[cur];
    const u8* Bsc = Bs[cur];
    ll af[4][2], bf[2][2];
#pragma unroll
    for (int h = 0; h < 2; ++h) {
      const int pw = ((h * 2 + p0) ^ fsw) * 16 + fb;
#pragma unroll
      for (int i = 0; i < 4; ++i)
        af[i][h] = *(const ll*)(Asc + (wm * 64 + i * 16 + lm) * 64 + pw);
#pragma unroll
      for (int j = 0; j < 2; ++j)
        bf[j][h] = *(const ll*)(Bsc + (wn * 32 + j * 16 + lm) * 64 + pw);
    }
#pragma unroll
    for (int h = 0; h < 2; ++h)
#pragma unroll
      for (int i = 0; i < 4; ++i)
#pragma unroll
        for (int j = 0; j < 2; ++j)
          acc[i][j] = __builtin_amdgcn_mfma_f32_16x16x32_fp8_fp8(af[i][h], bf[j][h], acc[i][j], 0, 0, 0);
    __syncthreads();
    cur ^= 1;
  }

  const float c0 = ws_w[b * 2], c1 = ws_w[b * 2 + 1];
  float* ob = out + (size_t)b * (S_ * D_);
  const int row0 = mt * 128 + wm * 64;
  const int col0 = nt * 64 + wn * 32;
#pragma unroll
  for (int j = 0; j < 2; ++j) {
    const int col = col0 + j * 16 + lm;
    const float bias = c0 * bout[e0 * D_ + col] + c1 * bout[e1 * D_ + col];
#pragma unroll
    for (int i = 0; i < 4; ++i)
#pragma unroll
      for (int r = 0; r < 4; ++r)
        ob[(size_t)(row0 + i * 16 + lq * 4 + r) * D_ + col] = acc[i][j][r] + bias;
  }
}

extern "C" void kernel_launch(void* const* d_in, const int* in_sizes, int n_in,
                              void* d_out, int out_size, void* d_ws, size_t ws_size,
                              hipStream_t stream) {
  const float* x     = (const float*)d_in[0];
  const float* noise = (const float*)d_in[1];
  const float* rw    = (const float*)d_in[2];
  const float* fiw   = (const float*)d_in[3];
  const float* fib   = (const float*)d_in[4];
  const float* fow   = (const float*)d_in[5];
  const float* fob   = (const float*)d_in[6];
  float* out = (float*)d_out;

  char* ws = (char*)d_ws;
  int*   ws_idx = (int*)ws;                                 // 16 ints
  float* ws_w   = (float*)(ws + 64);                        // 16 floats
  u8* xq    = (u8*)(ws + 256);                              // [B][S][D] fp8 (8 MB)
  u8* wtin  = xq + (size_t)B_ * S_ * D_;                    // [E][2H][D] fp8 (32 MB)
  u8* wtout = wtin + (size_t)E_ * 2 * H_ * D_;              // [E][D][H] fp8 (16 MB)
  u8* hid   = wtout + (size_t)E_ * D_ * H_;                 // [B*2][S][H] fp8 (32 MB)

  float* out_mixed  = out;
  float* out_logits = out + (size_t)B_ * S_ * D_;
  float* out_probs  = out_logits + B_ * E_;
  float* out_idx    = out_probs + B_ * E_;
  float* out_w      = out_idx + B_ * 2;

  prep_kernel<<<1 + NCAST + NT1 + NT2, 256, 0, stream>>>(
      x, noise, rw, fiw, fow, out_logits, out_probs, out_idx, out_w,
      ws_idx, ws_w, (unsigned int*)xq, wtin, wtout);
  gemm1_kernel<<<dim3(32, 8, 16), 256, 0, stream>>>(xq, wtin, fib, ws_idx, ws_w, hid);
  gemm2_kernel<<<dim3(16, 8, 8), 256, 0, stream>>>(hid, wtout, fob, ws_idx, ws_w, out_mixed);
}

// Round 3
// 439.879 us; speedup vs baseline: 1.0163x; 1.0163x over previous
//
#include <hip/hip_runtime.h>
#include <stdint.h>

#define B_ 8
#define S_ 1024
#define D_ 1024
#define H_ 2048
#define E_ 8
#define DN_ 256

typedef unsigned char u8;
typedef unsigned int u32;
typedef float f32x4 __attribute__((ext_vector_type(4)));
typedef long long ll;

// fp8 e4m3 (OCP on gfx950) converts
__device__ __forceinline__ u8 f2f8(float f) {
  return (u8)(__builtin_amdgcn_cvt_pk_fp8_f32(f, f, 0, false) & 0xff);
}
__device__ __forceinline__ u32 pk4f8(float a, float b, float c, float d) {
  int w = __builtin_amdgcn_cvt_pk_fp8_f32(a, b, 0, false);
  w = __builtin_amdgcn_cvt_pk_fp8_f32(c, d, w, true);
  return (u32)w;
}

// async global->LDS, 16B per lane. LDS dest is wave-uniform base; HW adds lane*16.
__device__ __forceinline__ void gll16(const void* g, void* l) {
  __builtin_amdgcn_global_load_lds(
      (__attribute__((address_space(1))) void*)g,
      (__attribute__((address_space(3))) void*)l, 16, 0, 0);
}

// swizzle value for tile row r (16B-pair XOR): 2-way-max bank conflicts on b64 frag reads
__device__ __forceinline__ int swz(int r) { return (r & 3) ^ ((r >> 2) & 1); }

// ---------------- merged prep: router + cast x + transpose/cast weights ----------------
// Packed-u32 transpose: each thread handles a 4x4 micro-tile; pk4f8 packs 4 rows
// into one u32 (bit-identical to per-element f2f8). LDS traffic is dword-granular.
template <int R, int C>
__device__ __forceinline__ void transpose_body(const float* __restrict__ ip,
                                               u8* __restrict__ op,
                                               int bx, int by, int t,
                                               u32 (&tl)[64][17]) {
  const int r0 = by * 64, c0 = bx * 64;
  const int rg = t >> 4;        // 0..15 row-group (4 rows)
  const int cg = t & 15;        // 0..15 col-group (4 cols)
  const float* p = ip + (size_t)(r0 + rg * 4) * C + c0 + cg * 4;
  float4 v0 = *(const float4*)(p);
  float4 v1 = *(const float4*)(p + C);
  float4 v2 = *(const float4*)(p + 2 * C);
  float4 v3 = *(const float4*)(p + 3 * C);
  tl[cg * 4 + 0][rg] = pk4f8(v0.x, v1.x, v2.x, v3.x);
  tl[cg * 4 + 1][rg] = pk4f8(v0.y, v1.y, v2.y, v3.y);
  tl[cg * 4 + 2][rg] = pk4f8(v0.z, v1.z, v2.z, v3.z);
  tl[cg * 4 + 3][rg] = pk4f8(v0.w, v1.w, v2.w, v3.w);
  __syncthreads();
  const int c = t >> 2, q = t & 3;  // col 0..63, 16B row-chunk 0..3
  uint4 w;
  w.x = tl[c][q * 4 + 0];
  w.y = tl[c][q * 4 + 1];
  w.z = tl[c][q * 4 + 2];
  w.w = tl[c][q * 4 + 3];
  *(uint4*)(op + (size_t)(c0 + c) * R + r0 + q * 16) = w;
}

#define NCAST (B_ * S_ * D_ / 1024)            // 8192 blocks (256 thr x float4)
#define NT1 ((2 * H_ / 64) * (D_ / 64) * E_)   // 8192 blocks
#define NT2 ((D_ / 64) * (H_ / 64) * E_)       // 4096 blocks

__global__ void __launch_bounds__(256) prep_kernel(
    const float* __restrict__ x, const float* __restrict__ noise,
    const float* __restrict__ rw, const float* __restrict__ fiw,
    const float* __restrict__ fow,
    float* __restrict__ out_logits, float* __restrict__ out_probs,
    float* __restrict__ out_idx, float* __restrict__ out_w,
    int* __restrict__ ws_idx, float* __restrict__ ws_w,
    u32* __restrict__ xq, u8* __restrict__ wtin,
    u8* __restrict__ wtout) {
  __shared__ __align__(16) u32 tile[64][17];
  const int t = threadIdx.x;
  int bid = blockIdx.x;

  if (bid == 0) {  // -------- router (hidden under the memory-bound blocks) ------
    float* sl = (float*)&tile[0][0];
    float* sp = sl + 64;
    {
      const int pair = t >> 2, sub = t & 3;      // 64 (b,e) pairs x 4 threads
      const int b = pair >> 3, e = pair & 7;
      float acc = 0.f;
      const int d0 = sub * 64;
      for (int d = d0; d < d0 + 64; ++d)
        acc += noise[b * DN_ + d] * rw[d * E_ + e];
      acc += __shfl_xor(acc, 1);
      acc += __shfl_xor(acc, 2);
      if (sub == 0) sl[pair] = acc;
    }
    __syncthreads();
    if (t < 64) {
      const int b = t >> 3;
      float L = sl[t];
      out_logits[t] = L;
      float m = -1e30f;
      for (int j = 0; j < 8; ++j) m = fmaxf(m, sl[b * 8 + j]);
      float s = 0.f;
      for (int j = 0; j < 8; ++j) s += __expf(sl[b * 8 + j] - m);
      float p = __expf(L - m) / s;
      out_probs[t] = p;
      sp[t] = p;
    }
    __syncthreads();
    if (t < 64 && (t & 7) == 0) {
      const int b = t >> 3;
      int a1 = 0; float v1 = sp[b * 8];
      for (int j = 1; j < 8; ++j) { float v = sp[b * 8 + j]; if (v > v1) { v1 = v; a1 = j; } }
      int a2 = -1; float v2 = -1e30f;
      for (int j = 0; j < 8; ++j) {
        if (j == a1) continue;
        float v = sp[b * 8 + j]; if (v > v2) { v2 = v; a2 = j; }
      }
      float sum = fmaxf(v1 + v2, 1e-8f);
      float w1 = v1 / sum, w2 = v2 / sum;
      out_idx[b * 2] = (float)a1; out_idx[b * 2 + 1] = (float)a2;
      out_w[b * 2] = w1; out_w[b * 2 + 1] = w2;
      ws_idx[b * 2] = a1; ws_idx[b * 2 + 1] = a2;
      ws_w[b * 2] = w1; ws_w[b * 2 + 1] = w2;
    }
    return;
  }
  bid -= 1;
  if (bid < NCAST) {  // -------- cast x -> fp8 --------
    const size_t i = (size_t)bid * 256 + t;
    float4 v = *((const float4*)x + i);
    xq[i] = pk4f8(v.x, v.y, v.z, v.w);
    return;
  }
  bid -= NCAST;
  if (bid < NT1) {  // -------- fc_in_w [E][D][2H] f32 -> [E][2H][D] fp8 --------
    const int bx = bid & 63, by = (bid >> 6) & 15, e = bid >> 10;
    transpose_body<D_, 2 * H_>(fiw + (size_t)e * D_ * 2 * H_,
                               wtin + (size_t)e * D_ * 2 * H_, bx, by, t, tile);
    return;
  }
  bid -= NT1;
  {  // -------- fc_out_w [E][H][D] f32 -> [E][D][H] fp8 --------
    const int bx = bid & 15, by = (bid >> 4) & 31, e = bid >> 9;
    transpose_body<H_, D_>(fow + (size_t)e * H_ * D_,
                           wtout + (size_t)e * H_ * D_, bx, by, t, tile);
  }
}

// ---------------- GEMM1: hidden = silu-gated(x @ W_in + b_in) * coeff  (fp8, BK=64) ----
// Block tile: 128 s-rows x 64 hid-cols (value + gate share one B-tile).
// T4 pipeline: double-buffered LDS, raw s_barrier + COUNTED vmcnt(4) — next tile's
// 4 loads stay in flight across the barrier; never drain to 0 in the main loop.
// __launch_bounds__(256,3): 170-reg budget avoids the R2 spill (WRITE_SIZE +8MB).
__global__ void __launch_bounds__(256, 3) gemm1_kernel(
    const u8* __restrict__ xq,      // [B][S][D] fp8
    const u8* __restrict__ wtin,    // [E][2H][D] fp8 (pre-transposed)
    const float* __restrict__ bin,  // [E][2H] f32
    const int* __restrict__ ws_idx, const float* __restrict__ ws_w,
    u8* __restrict__ hid)           // [B*2][S][H] fp8
{
  const int nt = blockIdx.x;   // 32 tiles of 64 hid-cols
  const int mt = blockIdx.y;   // 8 s-tiles
  const int z  = blockIdx.z;   // 16 = b*2+slot
  const int b  = z >> 1;
  const int e  = ws_idx[z] & 7;
  const float csc = ws_w[z];

  __shared__ u8 As[2][128 * 64];   // 16 KB
  __shared__ u8 Bs[2][128 * 64];   // 16 KB: rows 0-63 value cols, 64-127 gate cols

  const int t = threadIdx.x;
  const int wave = t >> 6, lane = t & 63;
  const int wm = wave >> 1, wn = wave & 1;
  const int lm = lane & 15, lq = lane >> 4;
  const int lrow4 = lane >> 2;
  const int kq = ((lane & 3) ^ swz(lrow4)) * 16;
  const int fsw = swz(lm);
  const int p0 = lq >> 1, fb = (lq & 1) * 8;

  const u8* Ab  = xq + (size_t)b * (S_ * D_) + (size_t)mt * 128 * D_;
  const u8* Bvb = wtin + (size_t)e * (2 * H_ * D_) + (size_t)nt * 64 * D_;
  const u8* Bgb = Bvb + (size_t)H_ * D_;

  auto stage = [&](int bf, int kt) {
    const int k0 = kt * 64 + kq;
    gll16(Ab + (size_t)(wave * 16 + lrow4) * D_ + k0, (char*)As[bf] + wave * 1024);
    gll16(Ab + (size_t)((wave + 4) * 16 + lrow4) * D_ + k0, (char*)As[bf] + (wave + 4) * 1024);
    gll16(Bvb + (size_t)(wave * 16 + lrow4) * D_ + k0, (char*)Bs[bf] + wave * 1024);
    gll16(Bgb + (size_t)(wave * 16 + lrow4) * D_ + k0, (char*)Bs[bf] + 4096 + wave * 1024);
  };

  const f32x4 vz = {0.f, 0.f, 0.f, 0.f};
  f32x4 accv[4][2], accg[4][2];
#pragma unroll
  for (int i = 0; i < 4; ++i)
#pragma unroll
    for (int j = 0; j < 2; ++j) { accv[i][j] = vz; accg[i][j] = vz; }

  auto compute = [&](int cb) {
    const u8* Asc = As[cb];
    const u8* Bsc = Bs[cb];
    ll af[4][2], bvf[2][2], bgf[2][2];
#pragma unroll
    for (int h = 0; h < 2; ++h) {
      const int pw = ((h * 2 + p0) ^ fsw) * 16 + fb;
#pragma unroll
      for (int i = 0; i < 4; ++i)
        af[i][h] = *(const ll*)(Asc + (wm * 64 + i * 16 + lm) * 64 + pw);
#pragma unroll
      for (int j = 0; j < 2; ++j) {
        bvf[j][h] = *(const ll*)(Bsc + (wn * 32 + j * 16 + lm) * 64 + pw);
        bgf[j][h] = *(const ll*)(Bsc + (64 + wn * 32 + j * 16 + lm) * 64 + pw);
      }
    }
#pragma unroll
    for (int h = 0; h < 2; ++h)
#pragma unroll
      for (int i = 0; i < 4; ++i)
#pragma unroll
        for (int j = 0; j < 2; ++j) {
          accv[i][j] = __builtin_amdgcn_mfma_f32_16x16x32_fp8_fp8(af[i][h], bvf[j][h], accv[i][j], 0, 0, 0);
          accg[i][j] = __builtin_amdgcn_mfma_f32_16x16x32_fp8_fp8(af[i][h], bgf[j][h], accg[i][j], 0, 0, 0);
        }
  };

  stage(0, 0);
#pragma unroll 2
  for (int kt = 0; kt < 14; ++kt) {                  // 7 unrolled pairs
    const int cb = kt & 1;
    stage(cb ^ 1, kt + 1);
    asm volatile("s_waitcnt vmcnt(4)" ::: "memory"); // cur tile landed; next 4 in flight
    __builtin_amdgcn_s_barrier();
    __builtin_amdgcn_sched_barrier(0);
    compute(cb);
    __builtin_amdgcn_sched_barrier(0);
    __builtin_amdgcn_s_barrier();
  }
  // kt = 14 (cb=0): stage last tile, compute buf0
  stage(1, 15);
  asm volatile("s_waitcnt vmcnt(4)" ::: "memory");
  __builtin_amdgcn_s_barrier();
  __builtin_amdgcn_sched_barrier(0);
  compute(0);
  __builtin_amdgcn_sched_barrier(0);
  __builtin_amdgcn_s_barrier();
  // kt = 15 (cb=1): final tile, full drain
  asm volatile("s_waitcnt vmcnt(0)" ::: "memory");
  __builtin_amdgcn_s_barrier();
  __builtin_amdgcn_sched_barrier(0);
  compute(1);

  u8* hb = hid + (size_t)z * (S_ * H_);
  const int row0 = mt * 128 + wm * 64;
  const int col0 = nt * 64 + wn * 32;
#pragma unroll
  for (int j = 0; j < 2; ++j) {
    const int col = col0 + j * 16 + lm;
    const float bvx = bin[e * 2 * H_ + col];
    const float bgx = bin[e * 2 * H_ + H_ + col];
#pragma unroll
    for (int i = 0; i < 4; ++i) {
#pragma unroll
      for (int r = 0; r < 4; ++r) {
        const int srow = row0 + i * 16 + lq * 4 + r;
        float v = accv[i][j][r] + bvx;
        float g = accg[i][j][r] + bgx;
        float hv = v * g / (1.f + __expf(-g)) * csc;   // value * silu(gate) * coeff
        hb[(size_t)srow * H_ + col] = f2f8(hv);
      }
    }
  }
}

// ---------------- GEMM2: mixed[b] = sum_slots hidden[b,slot] @ W_out[e] + bias (fp8) ---
// 128x64 tiles, T4 pipeline (counted vmcnt(3) + raw barriers), slot loop flattened
// so the prefetch crosses the slot boundary (64 K-steps total).
__global__ void __launch_bounds__(256, 3) gemm2_kernel(
    const u8* __restrict__ hid,     // [B*2][S][H] fp8 (coeff pre-applied)
    const u8* __restrict__ wtout,   // [E][D][H] fp8 (pre-transposed)
    const float* __restrict__ bout, // [E][D] f32
    const int* __restrict__ ws_idx, const float* __restrict__ ws_w,
    float* __restrict__ out)        // [B][S][D] f32
{
  const int nt = blockIdx.x;  // 16 d-tiles of 64
  const int mt = blockIdx.y;  // 8 s-tiles of 128
  const int b  = blockIdx.z;  // 8

  __shared__ u8 As[2][128 * 64];  // 16 KB
  __shared__ u8 Bs[2][64 * 64];   // 8 KB

  const int t = threadIdx.x;
  const int wave = t >> 6, lane = t & 63;
  const int wm = wave >> 1, wn = wave & 1;
  const int lm = lane & 15, lq = lane >> 4;
  const int lrow4 = lane >> 2;
  const int kq = ((lane & 3) ^ swz(lrow4)) * 16;
  const int fsw = swz(lm);
  const int p0 = lq >> 1, fb = (lq & 1) * 8;

  const int e0 = ws_idx[b * 2] & 7, e1 = ws_idx[b * 2 + 1] & 7;
  const u8* Ab0 = hid + ((size_t)(b * 2 + 0) * S_ + mt * 128) * H_;
  const u8* Ab1 = hid + ((size_t)(b * 2 + 1) * S_ + mt * 128) * H_;
  const u8* Bb0 = wtout + ((size_t)e0 * D_ + nt * 64) * H_;
  const u8* Bb1 = wtout + ((size_t)e1 * D_ + nt * 64) * H_;

  auto stage = [&](int bf, int it) {
    const u8* Ab = (it & 32) ? Ab1 : Ab0;
    const u8* Bb = (it & 32) ? Bb1 : Bb0;
    const int k0 = (it & 31) * 64 + kq;
    gll16(Ab + (size_t)(wave * 16 + lrow4) * H_ + k0, (char*)As[bf] + wave * 1024);
    gll16(Ab + (size_t)((wave + 4) * 16 + lrow4) * H_ + k0, (char*)As[bf] + (wave + 4) * 1024);
    gll16(Bb + (size_t)(wave * 16 + lrow4) * H_ + k0, (char*)Bs[bf] + wave * 1024);
  };

  const f32x4 vz = {0.f, 0.f, 0.f, 0.f};
  f32x4 acc[4][2];
#pragma unroll
  for (int i = 0; i < 4; ++i)
#pragma unroll
    for (int j = 0; j < 2; ++j) acc[i][j] = vz;

  auto compute = [&](int cb) {
    const u8* Asc = As[cb];
    const u8* Bsc = Bs[cb];
    ll af[4][2], bf[2][2];
#pragma unroll
    for (int h = 0; h < 2; ++h) {
      const int pw = ((h * 2 + p0) ^ fsw) * 16 + fb;
#pragma unroll
      for (int i = 0; i < 4; ++i)
        af[i][h] = *(const ll*)(Asc + (wm * 64 + i * 16 + lm) * 64 + pw);
#pragma unroll
      for (int j = 0; j < 2; ++j)
        bf[j][h] = *(const ll*)(Bsc + (wn * 32 + j * 16 + lm) * 64 + pw);
    }
#pragma unroll
    for (int h = 0; h < 2; ++h)
#pragma unroll
      for (int i = 0; i < 4; ++i)
#pragma unroll
        for (int j = 0; j < 2; ++j)
          acc[i][j] = __builtin_amdgcn_mfma_f32_16x16x32_fp8_fp8(af[i][h], bf[j][h], acc[i][j], 0, 0, 0);
  };

  stage(0, 0);
#pragma unroll 2
  for (int it = 0; it < 62; ++it) {                 // 31 unrolled pairs
    const int cb = it & 1;
    stage(cb ^ 1, it + 1);
    asm volatile("s_waitcnt vmcnt(3)" ::: "memory");
    __builtin_amdgcn_s_barrier();
    __builtin_amdgcn_sched_barrier(0);
    compute(cb);
    __builtin_amdgcn_sched_barrier(0);
    __builtin_amdgcn_s_barrier();
  }
  // it = 62 (cb=0)
  stage(1, 63);
  asm volatile("s_waitcnt vmcnt(3)" ::: "memory");
  __builtin_amdgcn_s_barrier();
  __builtin_amdgcn_sched_barrier(0);
  compute(0);
  __builtin_amdgcn_sched_barrier(0);
  __builtin_amdgcn_s_barrier();
  // it = 63 (cb=1)
  asm volatile("s_waitcnt vmcnt(0)" ::: "memory");
  __builtin_amdgcn_s_barrier();
  __builtin_amdgcn_sched_barrier(0);
  compute(1);

  const float c0 = ws_w[b * 2], c1 = ws_w[b * 2 + 1];
  float* ob = out + (size_t)b * (S_ * D_);
  const int row0 = mt * 128 + wm * 64;
  const int col0 = nt * 64 + wn * 32;
#pragma unroll
  for (int j = 0; j < 2; ++j) {
    const int col = col0 + j * 16 + lm;
    const float bias = c0 * bout[e0 * D_ + col] + c1 * bout[e1 * D_ + col];
#pragma unroll
    for (int i = 0; i < 4; ++i)
#pragma unroll
      for (int r = 0; r < 4; ++r)
        ob[(size_t)(row0 + i * 16 + lq * 4 + r) * D_ + col] = acc[i][j][r] + bias;
  }
}

extern "C" void kernel_launch(void* const* d_in, const int* in_sizes, int n_in,
                              void* d_out, int out_size, void* d_ws, size_t ws_size,
                              hipStream_t stream) {
  const float* x     = (const float*)d_in[0];
  const float* noise = (const float*)d_in[1];
  const float* rw    = (const float*)d_in[2];
  const float* fiw   = (const float*)d_in[3];
  const float* fib   = (const float*)d_in[4];
  const float* fow   = (const float*)d_in[5];
  const float* fob   = (const float*)d_in[6];
  float* out = (float*)d_out;

  char* ws = (char*)d_ws;
  int*   ws_idx = (int*)ws;                                 // 16 ints
  float* ws_w   = (float*)(ws + 64);                        // 16 floats
  u8* xq    = (u8*)(ws + 256);                              // [B][S][D] fp8 (8 MB)
  u8* wtin  = xq + (size_t)B_ * S_ * D_;                    // [E][2H][D] fp8 (32 MB)
  u8* wtout = wtin + (size_t)E_ * 2 * H_ * D_;              // [E][D][H] fp8 (16 MB)
  u8* hid   = wtout + (size_t)E_ * D_ * H_;                 // [B*2][S][H] fp8 (32 MB)

  float* out_mixed  = out;
  float* out_logits = out + (size_t)B_ * S_ * D_;
  float* out_probs  = out_logits + B_ * E_;
  float* out_idx    = out_probs + B_ * E_;
  float* out_w      = out_idx + B_ * 2;

  prep_kernel<<<1 + NCAST + NT1 + NT2, 256, 0, stream>>>(
      x, noise, rw, fiw, fow, out_logits, out_probs, out_idx, out_w,
      ws_idx, ws_w, (u32*)xq, wtin, wtout);
  gemm1_kernel<<<dim3(32, 8, 16), 256, 0, stream>>>(xq, wtin, fib, ws_idx, ws_w, hid);
  gemm2_kernel<<<dim3(16, 8, 8), 256, 0, stream>>>(hid, wtout, fob, ws_idx, ws_w, out_mixed);
}

// Round 4
// 425.073 us; speedup vs baseline: 1.0517x; 1.0348x over previous
//
#include <hip/hip_runtime.h>
#include <stdint.h>

#define B_ 8
#define S_ 1024
#define D_ 1024
#define H_ 2048
#define E_ 8
#define DN_ 256

typedef unsigned char u8;
typedef unsigned int u32;
typedef float f32x4 __attribute__((ext_vector_type(4)));
typedef long long ll;

// fp8 e4m3 (OCP on gfx950) converts
__device__ __forceinline__ u8 f2f8(float f) {
  return (u8)(__builtin_amdgcn_cvt_pk_fp8_f32(f, f, 0, false) & 0xff);
}
__device__ __forceinline__ u32 pk4f8(float a, float b, float c, float d) {
  int w = __builtin_amdgcn_cvt_pk_fp8_f32(a, b, 0, false);
  w = __builtin_amdgcn_cvt_pk_fp8_f32(c, d, w, true);
  return (u32)w;
}

// async global->LDS, 16B per lane. LDS dest is wave-uniform base; HW adds lane*16.
__device__ __forceinline__ void gll16(const void* g, void* l) {
  __builtin_amdgcn_global_load_lds(
      (__attribute__((address_space(1))) void*)g,
      (__attribute__((address_space(3))) void*)l, 16, 0, 0);
}

// ---------------- merged prep: router + cast x + transpose/cast weights ----------------
// 256-row x 64-col tiles: BOTH global sides 256B-coalesced (old version wrote
// scattered 64B chunks). pk4f8 packs 4 consecutive rows into one u32 (bit-identical
// numerics to per-element f2f8).
template <int R, int C>
__device__ __forceinline__ void transpose_body(const float* __restrict__ ip,
                                               u8* __restrict__ op,
                                               int bx, int by, int t,
                                               u32 (&tl)[64][65]) {
  const int r0 = by * 256, c0 = bx * 64;
  const int rg16 = t >> 4;      // 0..15
  const int cg = t & 15;        // 0..15 (group of 4 cols)
#pragma unroll
  for (int p = 0; p < 4; ++p) {
    const int rq = p * 16 + rg16;            // row-quad index 0..63 (rows rq*4..+3)
    const float* q = ip + (size_t)(r0 + rq * 4) * C + c0 + cg * 4;
    float4 v0 = *(const float4*)(q);
    float4 v1 = *(const float4*)(q + C);
    float4 v2 = *(const float4*)(q + 2 * C);
    float4 v3 = *(const float4*)(q + 3 * C);
    tl[cg * 4 + 0][rq] = pk4f8(v0.x, v1.x, v2.x, v3.x);
    tl[cg * 4 + 1][rq] = pk4f8(v0.y, v1.y, v2.y, v3.y);
    tl[cg * 4 + 2][rq] = pk4f8(v0.z, v1.z, v2.z, v3.z);
    tl[cg * 4 + 3][rq] = pk4f8(v0.w, v1.w, v2.w, v3.w);
  }
  __syncthreads();
  const int ch = t & 15;        // 16B chunk within the 256B output run
#pragma unroll
  for (int p = 0; p < 4; ++p) {
    const int c = p * 16 + (t >> 4);         // output row (= input col) 0..63
    uint4 w;
    w.x = tl[c][ch * 4 + 0];
    w.y = tl[c][ch * 4 + 1];
    w.z = tl[c][ch * 4 + 2];
    w.w = tl[c][ch * 4 + 3];
    *(uint4*)(op + (size_t)(c0 + c) * R + r0 + ch * 16) = w;
  }
}

#define NCAST (B_ * S_ * D_ / 1024)                 // 8192 blocks (256 thr x float4)
#define NT1 ((2 * H_ / 64) * (D_ / 256) * E_)       // 64*4*8 = 2048 blocks
#define NT2 ((D_ / 64) * (H_ / 256) * E_)           // 16*8*8 = 1024 blocks

__global__ void __launch_bounds__(256) prep_kernel(
    const float* __restrict__ x, const float* __restrict__ noise,
    const float* __restrict__ rw, const float* __restrict__ fiw,
    const float* __restrict__ fow,
    float* __restrict__ out_logits, float* __restrict__ out_probs,
    float* __restrict__ out_idx, float* __restrict__ out_w,
    int* __restrict__ ws_idx, float* __restrict__ ws_w,
    u32* __restrict__ xq, u8* __restrict__ wtin,
    u8* __restrict__ wtout) {
  __shared__ __align__(16) u32 tile[64][65];
  const int t = threadIdx.x;
  int bid = blockIdx.x;

  if (bid == 0) {  // -------- router (hidden under the memory-bound blocks) ------
    float* sl = (float*)&tile[0][0];
    float* sp = sl + 64;
    {
      const int pair = t >> 2, sub = t & 3;      // 64 (b,e) pairs x 4 threads
      const int b = pair >> 3, e = pair & 7;
      float acc = 0.f;
      const int d0 = sub * 64;
      for (int d = d0; d < d0 + 64; ++d)
        acc += noise[b * DN_ + d] * rw[d * E_ + e];
      acc += __shfl_xor(acc, 1);
      acc += __shfl_xor(acc, 2);
      if (sub == 0) sl[pair] = acc;
    }
    __syncthreads();
    if (t < 64) {
      const int b = t >> 3;
      float L = sl[t];
      out_logits[t] = L;
      float m = -1e30f;
      for (int j = 0; j < 8; ++j) m = fmaxf(m, sl[b * 8 + j]);
      float s = 0.f;
      for (int j = 0; j < 8; ++j) s += __expf(sl[b * 8 + j] - m);
      float p = __expf(L - m) / s;
      out_probs[t] = p;
      sp[t] = p;
    }
    __syncthreads();
    if (t < 64 && (t & 7) == 0) {
      const int b = t >> 3;
      int a1 = 0; float v1 = sp[b * 8];
      for (int j = 1; j < 8; ++j) { float v = sp[b * 8 + j]; if (v > v1) { v1 = v; a1 = j; } }
      int a2 = -1; float v2 = -1e30f;
      for (int j = 0; j < 8; ++j) {
        if (j == a1) continue;
        float v = sp[b * 8 + j]; if (v > v2) { v2 = v; a2 = j; }
      }
      float sum = fmaxf(v1 + v2, 1e-8f);
      float w1 = v1 / sum, w2 = v2 / sum;
      out_idx[b * 2] = (float)a1; out_idx[b * 2 + 1] = (float)a2;
      out_w[b * 2] = w1; out_w[b * 2 + 1] = w2;
      ws_idx[b * 2] = a1; ws_idx[b * 2 + 1] = a2;
      ws_w[b * 2] = w1; ws_w[b * 2 + 1] = w2;
    }
    return;
  }
  bid -= 1;
  if (bid < NCAST) {  // -------- cast x -> fp8 --------
    const size_t i = (size_t)bid * 256 + t;
    float4 v = *((const float4*)x + i);
    xq[i] = pk4f8(v.x, v.y, v.z, v.w);
    return;
  }
  bid -= NCAST;
  if (bid < NT1) {  // -------- fc_in_w [E][D][2H] f32 -> [E][2H][D] fp8 --------
    const int bx = bid & 63, by = (bid >> 6) & 3, e = bid >> 8;
    transpose_body<D_, 2 * H_>(fiw + (size_t)e * D_ * 2 * H_,
                               wtin + (size_t)e * D_ * 2 * H_, bx, by, t, tile);
    return;
  }
  bid -= NT1;
  {  // -------- fc_out_w [E][H][D] f32 -> [E][D][H] fp8 --------
    const int bx = bid & 15, by = (bid >> 4) & 7, e = bid >> 7;
    transpose_body<H_, D_>(fow + (size_t)e * H_ * D_,
                           wtout + (size_t)e * H_ * D_, bx, by, t, tile);
  }
}

// ---------------- GEMM1: hidden = silu-gated(x @ W_in + b_in) * coeff  (fp8) ----------
// Block tile: 128 s-rows x 64 hid-cols (value + gate share one A-tile), BK=128.
// Single-buffer 2-barrier loop (verified fastest structure); BK=64->128 halves the
// number of vmcnt(0)-drain + barrier events (8 K-iters, 64 MFMA per barrier pair).
// LDS rows are 128B (8 x 16B slots), XOR-swizzled by row&7 for 2-way-max conflicts.
__global__ void __launch_bounds__(256, 4) gemm1_kernel(
    const u8* __restrict__ xq,      // [B][S][D] fp8
    const u8* __restrict__ wtin,    // [E][2H][D] fp8 (pre-transposed)
    const float* __restrict__ bin,  // [E][2H] f32
    const int* __restrict__ ws_idx, const float* __restrict__ ws_w,
    u8* __restrict__ hid)           // [B*2][S][H] fp8
{
  const int nt = blockIdx.x;   // 32 tiles of 64 hid-cols
  const int mt = blockIdx.y;   // 8 s-tiles
  const int z  = blockIdx.z;   // 16 = b*2+slot
  const int b  = z >> 1;
  const int e  = ws_idx[z] & 7;
  const float csc = ws_w[z];

  __shared__ u8 As[128 * 128];   // 16 KB: 128 s-rows x 128 k
  __shared__ u8 Bs[128 * 128];   // 16 KB: rows 0-63 value cols, 64-127 gate cols

  const int t = threadIdx.x;
  const int wave = t >> 6, lane = t & 63;
  const int wm = wave >> 1, wn = wave & 1;
  const int lm = lane & 15, lq = lane >> 4;
  const int lrow8 = lane >> 3;                   // staging row within 8-row chunk
  const int kq = ((lane & 7) ^ lrow8) * 16;      // swizzled 16B-slot fetch offset
  const int fsw = lm & 7;                        // fragment-read row swizzle key
  const int p0 = lq >> 1, fb = (lq & 1) * 8;     // slot sub-index / byte-in-slot

  const u8* Ab  = xq + (size_t)b * (S_ * D_) + (size_t)mt * 128 * D_;
  const u8* Bvb = wtin + (size_t)e * (2 * H_ * D_) + (size_t)nt * 64 * D_;
  const u8* Bgb = Bvb + (size_t)H_ * D_;

  const f32x4 vz = {0.f, 0.f, 0.f, 0.f};
  f32x4 accv[4][2], accg[4][2];
#pragma unroll
  for (int i = 0; i < 4; ++i)
#pragma unroll
    for (int j = 0; j < 2; ++j) { accv[i][j] = vz; accg[i][j] = vz; }

  for (int kt = 0; kt < D_ / 128; ++kt) {        // 8 k-iters
    const int k0 = kt * 128 + kq;
    // A: 16 chunks of 8 rows; wave stages chunks w, w+4, w+8, w+12
    gll16(Ab + (size_t)(wave * 8 + lrow8) * D_ + k0, (char*)As + wave * 1024);
    gll16(Ab + (size_t)((wave + 4) * 8 + lrow8) * D_ + k0, (char*)As + (wave + 4) * 1024);
    gll16(Ab + (size_t)((wave + 8) * 8 + lrow8) * D_ + k0, (char*)As + (wave + 8) * 1024);
    gll16(Ab + (size_t)((wave + 12) * 8 + lrow8) * D_ + k0, (char*)As + (wave + 12) * 1024);
    // B value: chunks w, w+4 (rows 0-63); gate: chunks 8+w, 12+w (rows 64-127)
    gll16(Bvb + (size_t)(wave * 8 + lrow8) * D_ + k0, (char*)Bs + wave * 1024);
    gll16(Bvb + (size_t)((wave + 4) * 8 + lrow8) * D_ + k0, (char*)Bs + (wave + 4) * 1024);
    gll16(Bgb + (size_t)(wave * 8 + lrow8) * D_ + k0, (char*)Bs + (8 + wave) * 1024);
    gll16(Bgb + (size_t)((wave + 4) * 8 + lrow8) * D_ + k0, (char*)Bs + (12 + wave) * 1024);
    __syncthreads();
#pragma unroll
    for (int hg = 0; hg < 2; ++hg) {             // two half-groups keep frag regs small
      ll af[4][2], bvf[2][2], bgf[2][2];
#pragma unroll
      for (int h2 = 0; h2 < 2; ++h2) {
        const int pw = ((((hg * 2 + h2) * 2 + p0) ^ fsw)) * 16 + fb;
#pragma unroll
        for (int i = 0; i < 4; ++i)
          af[i][h2] = *(const ll*)(As + (wm * 64 + i * 16 + lm) * 128 + pw);
#pragma unroll
        for (int j = 0; j < 2; ++j) {
          bvf[j][h2] = *(const ll*)(Bs + (wn * 32 + j * 16 + lm) * 128 + pw);
          bgf[j][h2] = *(const ll*)(Bs + (64 + wn * 32 + j * 16 + lm) * 128 + pw);
        }
      }
#pragma unroll
      for (int h2 = 0; h2 < 2; ++h2)
#pragma unroll
        for (int i = 0; i < 4; ++i)
#pragma unroll
          for (int j = 0; j < 2; ++j) {
            accv[i][j] = __builtin_amdgcn_mfma_f32_16x16x32_fp8_fp8(af[i][h2], bvf[j][h2], accv[i][j], 0, 0, 0);
            accg[i][j] = __builtin_amdgcn_mfma_f32_16x16x32_fp8_fp8(af[i][h2], bgf[j][h2], accg[i][j], 0, 0, 0);
          }
    }
    __syncthreads();
  }

  u8* hb = hid + (size_t)z * (S_ * H_);
  const int row0 = mt * 128 + wm * 64;
  const int col0 = nt * 64 + wn * 32;
#pragma unroll
  for (int j = 0; j < 2; ++j) {
    const int col = col0 + j * 16 + lm;
    const float bvx = bin[e * 2 * H_ + col];
    const float bgx = bin[e * 2 * H_ + H_ + col];
#pragma unroll
    for (int i = 0; i < 4; ++i) {
#pragma unroll
      for (int r = 0; r < 4; ++r) {
        const int srow = row0 + i * 16 + lq * 4 + r;
        float v = accv[i][j][r] + bvx;
        float g = accg[i][j][r] + bgx;
        float hv = v * g / (1.f + __expf(-g)) * csc;   // value * silu(gate) * coeff
        hb[(size_t)srow * H_ + col] = f2f8(hv);
      }
    }
  }
}

// ---------------- GEMM2: mixed[b] = sum_slots hidden[b,slot] @ W_out[e] + bias (fp8) ---
// 128x64 tiles, BK=128, single-buffer 2-barrier loop, slot loop flattened
// (32 K-steps total). Grid 16x8x8 = 1024 = exactly one 4-blocks/CU batch.
__global__ void __launch_bounds__(256, 4) gemm2_kernel(
    const u8* __restrict__ hid,     // [B*2][S][H] fp8 (coeff pre-applied)
    const u8* __restrict__ wtout,   // [E][D][H] fp8 (pre-transposed)
    const float* __restrict__ bout, // [E][D] f32
    const int* __restrict__ ws_idx, const float* __restrict__ ws_w,
    float* __restrict__ out)        // [B][S][D] f32
{
  const int nt = blockIdx.x;  // 16 d-tiles of 64
  const int mt = blockIdx.y;  // 8 s-tiles of 128
  const int b  = blockIdx.z;  // 8

  __shared__ u8 As[128 * 128];  // 16 KB
  __shared__ u8 Bs[64 * 128];   // 8 KB

  const int t = threadIdx.x;
  const int wave = t >> 6, lane = t & 63;
  const int wm = wave >> 1, wn = wave & 1;
  const int lm = lane & 15, lq = lane >> 4;
  const int lrow8 = lane >> 3;
  const int kq = ((lane & 7) ^ lrow8) * 16;
  const int fsw = lm & 7;
  const int p0 = lq >> 1, fb = (lq & 1) * 8;

  const int e0 = ws_idx[b * 2] & 7, e1 = ws_idx[b * 2 + 1] & 7;
  const u8* Ab0 = hid + ((size_t)(b * 2 + 0) * S_ + mt * 128) * H_;
  const u8* Ab1 = hid + ((size_t)(b * 2 + 1) * S_ + mt * 128) * H_;
  const u8* Bb0 = wtout + ((size_t)e0 * D_ + nt * 64) * H_;
  const u8* Bb1 = wtout + ((size_t)e1 * D_ + nt * 64) * H_;

  const f32x4 vz = {0.f, 0.f, 0.f, 0.f};
  f32x4 acc[4][2];
#pragma unroll
  for (int i = 0; i < 4; ++i)
#pragma unroll
    for (int j = 0; j < 2; ++j) acc[i][j] = vz;

  for (int it = 0; it < 32; ++it) {              // 2 slots x 16 k-iters
    const u8* Ab = (it & 16) ? Ab1 : Ab0;
    const u8* Bb = (it & 16) ? Bb1 : Bb0;
    const int k0 = (it & 15) * 128 + kq;
    gll16(Ab + (size_t)(wave * 8 + lrow8) * H_ + k0, (char*)As + wave * 1024);
    gll16(Ab + (size_t)((wave + 4) * 8 + lrow8) * H_ + k0, (char*)As + (wave + 4) * 1024);
    gll16(Ab + (size_t)((wave + 8) * 8 + lrow8) * H_ + k0, (char*)As + (wave + 8) * 1024);
    gll16(Ab + (size_t)((wave + 12) * 8 + lrow8) * H_ + k0, (char*)As + (wave + 12) * 1024);
    gll16(Bb + (size_t)(wave * 8 + lrow8) * H_ + k0, (char*)Bs + wave * 1024);
    gll16(Bb + (size_t)((wave + 4) * 8 + lrow8) * H_ + k0, (char*)Bs + (wave + 4) * 1024);
    __syncthreads();
#pragma unroll
    for (int hg = 0; hg < 2; ++hg) {
      ll af[4][2], bf[2][2];
#pragma unroll
      for (int h2 = 0; h2 < 2; ++h2) {
        const int pw = ((((hg * 2 + h2) * 2 + p0) ^ fsw)) * 16 + fb;
#pragma unroll
        for (int i = 0; i < 4; ++i)
          af[i][h2] = *(const ll*)(As + (wm * 64 + i * 16 + lm) * 128 + pw);
#pragma unroll
        for (int j = 0; j < 2; ++j)
          bf[j][h2] = *(const ll*)(Bs + (wn * 32 + j * 16 + lm) * 128 + pw);
      }
#pragma unroll
      for (int h2 = 0; h2 < 2; ++h2)
#pragma unroll
        for (int i = 0; i < 4; ++i)
#pragma unroll
          for (int j = 0; j < 2; ++j)
            acc[i][j] = __builtin_amdgcn_mfma_f32_16x16x32_fp8_fp8(af[i][h2], bf[j][h2], acc[i][j], 0, 0, 0);
    }
    __syncthreads();
  }

  const float c0 = ws_w[b * 2], c1 = ws_w[b * 2 + 1];
  float* ob = out + (size_t)b * (S_ * D_);
  const int row0 = mt * 128 + wm * 64;
  const int col0 = nt * 64 + wn * 32;
#pragma unroll
  for (int j = 0; j < 2; ++j) {
    const int col = col0 + j * 16 + lm;
    const float bias = c0 * bout[e0 * D_ + col] + c1 * bout[e1 * D_ + col];
#pragma unroll
    for (int i = 0; i < 4; ++i)
#pragma unroll
      for (int r = 0; r < 4; ++r)
        ob[(size_t)(row0 + i * 16 + lq * 4 + r) * D_ + col] = acc[i][j][r] + bias;
  }
}

extern "C" void kernel_launch(void* const* d_in, const int* in_sizes, int n_in,
                              void* d_out, int out_size, void* d_ws, size_t ws_size,
                              hipStream_t stream) {
  const float* x     = (const float*)d_in[0];
  const float* noise = (const float*)d_in[1];
  const float* rw    = (const float*)d_in[2];
  const float* fiw   = (const float*)d_in[3];
  const float* fib   = (const float*)d_in[4];
  const float* fow   = (const float*)d_in[5];
  const float* fob   = (const float*)d_in[6];
  float* out = (float*)d_out;

  char* ws = (char*)d_ws;
  int*   ws_idx = (int*)ws;                                 // 16 ints
  float* ws_w   = (float*)(ws + 64);                        // 16 floats
  u8* xq    = (u8*)(ws + 256);                              // [B][S][D] fp8 (8 MB)
  u8* wtin  = xq + (size_t)B_ * S_ * D_;                    // [E][2H][D] fp8 (32 MB)
  u8* wtout = wtin + (size_t)E_ * 2 * H_ * D_;              // [E][D][H] fp8 (16 MB)
  u8* hid   = wtout + (size_t)E_ * D_ * H_;                 // [B*2][S][H] fp8 (32 MB)

  float* out_mixed  = out;
  float* out_logits = out + (size_t)B_ * S_ * D_;
  float* out_probs  = out_logits + B_ * E_;
  float* out_idx    = out_probs + B_ * E_;
  float* out_w      = out_idx + B_ * 2;

  prep_kernel<<<1 + NCAST + NT1 + NT2, 256, 0, stream>>>(
      x, noise, rw, fiw, fow, out_logits, out_probs, out_idx, out_w,
      ws_idx, ws_w, (u32*)xq, wtin, wtout);
  gemm1_kernel<<<dim3(32, 8, 16), 256, 0, stream>>>(xq, wtin, fib, ws_idx, ws_w, hid);
  gemm2_kernel<<<dim3(16, 8, 8), 256, 0, stream>>>(hid, wtout, fob, ws_idx, ws_w, out_mixed);
}